// Round 18
// baseline (3134.263 us; speedup 1.0000x reference)
//
#include <hip/hip_runtime.h>
#include <hip/hip_fp16.h>
#include <stdint.h>
#include <math.h>

#define HWS 16384
#define NPIX (16 * HWS)
#define T 256

typedef _Float16 h2 __attribute__((ext_vector_type(2)));
typedef float f4v __attribute__((ext_vector_type(4)));
union U4 { f4v v; float f[4]; h2 h[4]; };

// d_ws slot offsets (4B slots). Rows interleaved so one row base + immediate
// offsets serves a whole c-iteration. Weights via s_load (SGPR) — r15/r16
// falsified the VMEM and LDS weight paths.
enum {
  H_W1P = 0,      // [24cp][24]  rb1 pairs
  F_B1  = 576,    // 24
  H_RB2 = 600,    // [24op][28]: W2row(2op)[12] | W2row(2op+1)[12] | {b2e,b2o,xse,xso}
  H_SC  = 1272,   // [48c][52]: M1A[12]|M1B[12]|M2A[12]|M2B[12]|{c1a,c1b,c2a,c2b}
  F_D4  = 3768,   // [24][4] {d1a,d1b,d2a,d2b}
  F_E4  = 3864,   // 4
  H_PV  = 3868,   // [48c][48]: P1[24]|P2[24]
  F_Q4  = 6172,   // [24][4] {q1l,q1h,q2l,q2h}
  F_BE1 = 6268,   // 24
  F_CFT = 6292,   // f32 [96][48] cin-major (k0 only)
  F_BCF = 10900,  // 48
  F_WE1 = 10948,  // f32 [24][48] o-major (k0 only)
  F_WE2 = 12100,  // [24op][52]: we2row(2op)[24] | we2row(2op+1)[24] | {be2e,be2o,0,0}
  WS_TOTAL = 13348
};

struct PtrPack { const float* p[48]; };

__device__ __forceinline__ void bnst(const PtrPack& P, int bnb, int o, float& s, float& t) {
  float g = P.p[bnb][o], be = P.p[bnb + 1][o], m = P.p[bnb + 2][o], v = P.p[bnb + 3][o];
  s = g / sqrtf(v + 1e-5f);
  t = be - m * s;
}
__device__ __forceinline__ float KFv(const PtrPack& P, const float* kw, int bnb, int ok, int j) {
  float s, t; bnst(P, bnb, ok, s, t);
  float a = 0.f;
  for (int cc = 0; cc < 48; cc++) a += kw[ok * 48 + cc] * P.p[46][cc * 24 + j];
  return s * a;
}
__device__ __forceinline__ float BFv(const PtrPack& P, const float* kw, const float* kb, int bnb, int ok) {
  float s, t; bnst(P, bnb, ok, s, t);
  float a = kb[ok];
  for (int cc = 0; cc < 48; cc++) a += kw[ok * 48 + cc] * P.p[47][cc];
  return s * a + t;
}
__device__ __forceinline__ float WQf(const PtrPack& P, int o, int c) { float s, t; bnst(P, 16, o, s, t); return s * P.p[14][o * 48 + c]; }
__device__ __forceinline__ float BQf(const PtrPack& P, int o) { float s, t; bnst(P, 16, o, s, t); return s * P.p[15][o] + t; }
__device__ __forceinline__ float WVf(const PtrPack& P, int o, int c) { float s, t; bnst(P, 22, o, s, t); return s * P.p[20][o * 48 + c]; }
__device__ __forceinline__ float BVf(const PtrPack& P, int o) { float s, t; bnst(P, 22, o, s, t); return s * P.p[21][o] + t; }

__device__ float w1v(const PtrPack& P, int c, int o) { float s, t; bnst(P, 4, o, s, t); return s * P.p[2][o * 48 + c]; }
__device__ float w2v(const PtrPack& P, int o, int c) { float s, t; bnst(P, 10, o, s, t); return s * P.p[8][o * 24 + c]; }
__device__ float m_v(const PtrPack& P, int which, int c, int j) {
  float a = 0.f;
  if (which == 0)      for (int ok = 0; ok < 24; ok++) a += KFv(P, P.p[26], 28, ok, j) * WQf(P, ok, c);
  else if (which == 1) for (int ok = 0; ok < 24; ok++) a += KFv(P, P.p[26], 28, ok, j) * WQf(P, 24 + ok, c);
  else if (which == 2) for (int ok = 0; ok < 24; ok++) a += KFv(P, P.p[32], 34, ok, j) * WQf(P, ok, c);
  else                 for (int ok = 0; ok < 24; ok++) a += KFv(P, P.p[32], 34, ok, j) * WQf(P, 24 + ok, c);
  return a;
}
__device__ float p_v(const PtrPack& P, int which, int c, int o) {
  float a = 0.f;
  if (which == 0)      for (int jj = 0; jj < 24; jj++) a += P.p[44][o * 48 + jj] * WVf(P, jj, c);
  else if (which == 1) for (int jj = 0; jj < 24; jj++) a += P.p[44][o * 48 + jj] * WVf(P, 24 + jj, c);
  else if (which == 2) for (int jj = 0; jj < 24; jj++) a += P.p[44][o * 48 + 24 + jj] * WVf(P, jj, c);
  else                 for (int jj = 0; jj < 24; jj++) a += P.p[44][o * 48 + 24 + jj] * WVf(P, 24 + jj, c);
  return a;
}
__device__ float c_v(const PtrPack& P, int e, int c) {
  float a = 0.f;
  if (e == 0)      for (int ok = 0; ok < 24; ok++) a += BFv(P, P.p[26], P.p[27], 28, ok) * WQf(P, ok, c);
  else if (e == 1) for (int ok = 0; ok < 24; ok++) a += BFv(P, P.p[26], P.p[27], 28, ok) * WQf(P, 24 + ok, c);
  else if (e == 2) for (int ok = 0; ok < 24; ok++) a += BFv(P, P.p[32], P.p[33], 34, ok) * WQf(P, ok, c);
  else             for (int ok = 0; ok < 24; ok++) a += BFv(P, P.p[32], P.p[33], 34, ok) * WQf(P, 24 + ok, c);
  return a;
}
__device__ float d_v(const PtrPack& P, int e, int j) {
  float a = 0.f;
  if (e == 0)      for (int ok = 0; ok < 24; ok++) a += KFv(P, P.p[26], 28, ok, j) * BQf(P, ok);
  else if (e == 1) for (int ok = 0; ok < 24; ok++) a += KFv(P, P.p[26], 28, ok, j) * BQf(P, 24 + ok);
  else if (e == 2) for (int ok = 0; ok < 24; ok++) a += KFv(P, P.p[32], 34, ok, j) * BQf(P, ok);
  else             for (int ok = 0; ok < 24; ok++) a += KFv(P, P.p[32], 34, ok, j) * BQf(P, 24 + ok);
  return a;
}
__device__ float e_v(const PtrPack& P, int e) {
  float a = 0.f;
  if (e == 0)      for (int ok = 0; ok < 24; ok++) a += BFv(P, P.p[26], P.p[27], 28, ok) * BQf(P, ok);
  else if (e == 1) for (int ok = 0; ok < 24; ok++) a += BFv(P, P.p[26], P.p[27], 28, ok) * BQf(P, 24 + ok);
  else if (e == 2) for (int ok = 0; ok < 24; ok++) a += BFv(P, P.p[32], P.p[33], 34, ok) * BQf(P, ok);
  else             for (int ok = 0; ok < 24; ok++) a += BFv(P, P.p[32], P.p[33], 34, ok) * BQf(P, 24 + ok);
  return a;
}
__device__ float q_v(const PtrPack& P, int e, int o) {
  float a = 0.f;
  if (e == 0)      for (int jj = 0; jj < 24; jj++) a += P.p[44][o * 48 + jj] * BVf(P, jj);
  else if (e == 1) for (int jj = 0; jj < 24; jj++) a += P.p[44][o * 48 + jj] * BVf(P, 24 + jj);
  else if (e == 2) for (int jj = 0; jj < 24; jj++) a += P.p[44][o * 48 + 24 + jj] * BVf(P, jj);
  else             for (int jj = 0; jj < 24; jj++) a += P.p[44][o * 48 + 24 + jj] * BVf(P, 24 + jj);
  return a;
}

__device__ __forceinline__ float packh2(float a, float b) {
  __half2 h = __floats2half2_rn(a, b);
  union { __half2 h; float f; } x; x.h = h; return x.f;
}

__global__ void fold_kernel(PtrPack P, float* __restrict__ W) {
  int i = blockIdx.x * blockDim.x + threadIdx.x;
  if (i >= WS_TOTAL) return;
  float s, t;
  if (i < F_B1) { int cp = i / 24, o = i % 24; W[i] = packh2(w1v(P, 2 * cp, o), w1v(P, 2 * cp + 1, o)); }
  else if (i < H_RB2) { int o = i - F_B1; bnst(P, 4, o, s, t); W[i] = s * P.p[3][o] + t; }
  else if (i < H_SC) {
    int j = i - H_RB2; int op = j / 28, r = j % 28;
    if (r < 12)       W[i] = packh2(w2v(P, 2 * op, 2 * r), w2v(P, 2 * op, 2 * r + 1));
    else if (r < 24)  { int rr = r - 12; W[i] = packh2(w2v(P, 2 * op + 1, 2 * rr), w2v(P, 2 * op + 1, 2 * rr + 1)); }
    else {
      int e = r - 24; int o2 = 2 * op + (e & 1);
      bnst(P, 10, o2, s, t);
      W[i] = (e < 2) ? (s * P.p[9][o2] + t) : s;
    }
  }
  else if (i < F_D4) {
    int j = i - H_SC; int c = j / 52, r = j % 52;
    if (r < 12)       W[i] = packh2(m_v(P, 0, c, 2 * r), m_v(P, 0, c, 2 * r + 1));
    else if (r < 24)  { int rr = r - 12; W[i] = packh2(m_v(P, 1, c, 2 * rr), m_v(P, 1, c, 2 * rr + 1)); }
    else if (r < 36)  { int rr = r - 24; W[i] = packh2(m_v(P, 2, c, 2 * rr), m_v(P, 2, c, 2 * rr + 1)); }
    else if (r < 48)  { int rr = r - 36; W[i] = packh2(m_v(P, 3, c, 2 * rr), m_v(P, 3, c, 2 * rr + 1)); }
    else              W[i] = c_v(P, r - 48, c);
  }
  else if (i < F_E4) { int j = i - F_D4; W[i] = d_v(P, j % 4, j / 4); }
  else if (i < H_PV) { W[i] = e_v(P, i - F_E4); }
  else if (i < F_Q4) {
    int j = i - H_PV; int c = j / 48, r = j % 48;
    if (r < 24) W[i] = packh2(p_v(P, 0, c, r), p_v(P, 1, c, r));
    else        { int rr = r - 24; W[i] = packh2(p_v(P, 2, c, rr), p_v(P, 3, c, rr)); }
  }
  else if (i < F_BE1) { int j = i - F_Q4; W[i] = q_v(P, j % 4, j / 4); }
  else if (i < F_CFT) { W[i] = P.p[45][i - F_BE1]; }
  else if (i < F_BCF) { int j = i - F_CFT; int cin = j / 48, o = j % 48; bnst(P, 40, o, s, t); W[i] = s * P.p[38][o * 96 + cin]; }
  else if (i < F_WE1) { int o = i - F_BCF; bnst(P, 40, o, s, t); W[i] = s * P.p[39][o] + t; }
  else if (i < F_WE2) { W[i] = P.p[44][i - F_WE1]; }
  else {
    int j = i - F_WE2; int op = j / 52, r = j % 52;
    if (r < 24)       W[i] = P.p[46][(2 * op) * 24 + r];
    else if (r < 48)  W[i] = P.p[46][(2 * op + 1) * 24 + (r - 24)];
    else if (r == 48) W[i] = P.p[47][2 * op];
    else if (r == 49) W[i] = P.p[47][2 * op + 1];
    else              W[i] = 0.f;
  }
}

// ---------------- fused per-pixel forward, X fully in registers ----------------
// Every loop that indexes X is FULLY unrolled (rule #20: no runtime register
// indexing). LDS usage: zero.

__device__ __forceinline__ float gelu_f(float x) {
  return 0.5f * x * (1.f + erff(x * 0.70710678118654752440f));
}
__device__ __forceinline__ float fdot2f(h2 a, h2 b, float c) {
#if __has_builtin(__builtin_amdgcn_fdot2)
  return __builtin_amdgcn_fdot2(a, b, c, false);
#else
  return fmaf((float)a[0], (float)b[0], fmaf((float)a[1], (float)b[1], c));
#endif
}
__device__ __forceinline__ h2 ash2(__half2 v) {
  union { __half2 a; h2 h; } u; u.a = v; return u.h;
}
// RNE packing (pkrtz's biased truncation failed accuracy in round 13)
__device__ __forceinline__ h2 pk(float a, float b) {
  return ash2(__floats2half2_rn(a, b));
}
__device__ __forceinline__ U4 ld4(const float* __restrict__ W, int off) {
  U4 u; u.v = *(const f4v*)&W[off]; return u;
}

__global__ __launch_bounds__(T)
void fused_main(const float* __restrict__ x0g,
                const float* __restrict__ x1g,
                const float* __restrict__ W,
                float* __restrict__ out) {
  const int tid = threadIdx.x;
  const int p = blockIdx.x * T + tid;
  const int b = p >> 14;
  const int n = p & (HWS - 1);

  h2 X[2][24];  // register-resident state; indexed only by unrolled constants
  {
    const float* px0 = x0g + (size_t)b * 48 * HWS + n;
    const float* px1 = x1g + (size_t)b * 48 * HWS + n;
#pragma unroll
    for (int cp = 0; cp < 24; cp++) {
      X[0][cp] = pk(px0[(size_t)(2 * cp) * HWS], px0[(size_t)(2 * cp + 1) * HWS]);
      X[1][cp] = pk(px1[(size_t)(2 * cp) * HWS], px1[(size_t)(2 * cp + 1) * HWS]);
    }
  }

  float h[24];

#pragma unroll 1
  for (int k = 0; k < 4; k++) {
    // ---- residual blocks (X in regs) ----
#pragma unroll
    for (int s = 0; s < 2; s++) {
      float r[24];
#pragma unroll
      for (int q = 0; q < 6; q++) {
        U4 bq = ld4(W, F_B1 + 4 * q);
#pragma unroll
        for (int e = 0; e < 4; e++) r[4 * q + e] = bq.f[e];
      }
#pragma unroll
      for (int cp = 0; cp < 24; cp++) {
        h2 xp = X[s][cp];
        const int base = H_W1P + cp * 24;
#pragma unroll
        for (int q = 0; q < 6; q++) {
          U4 w = ld4(W, base + 4 * q);
#pragma unroll
          for (int e = 0; e < 4; e++) r[4 * q + e] = fdot2f(w.h[e], xp, r[4 * q + e]);
        }
      }
      h2 rp[12];
#pragma unroll
      for (int j = 0; j < 12; j++) rp[j] = pk(fmaxf(r[2 * j], 0.f), fmaxf(r[2 * j + 1], 0.f));

#pragma unroll
      for (int op = 0; op < 24; op++) {
        const int base = H_RB2 + op * 28;
        U4 bx = ld4(W, base + 24);
        float a0 = bx.f[0], a1 = bx.f[1];
#pragma unroll
        for (int q = 0; q < 3; q++) {
          U4 w = ld4(W, base + 4 * q);
#pragma unroll
          for (int e = 0; e < 4; e++) a0 = fdot2f(w.h[e], rp[4 * q + e], a0);
        }
#pragma unroll
        for (int q = 0; q < 3; q++) {
          U4 w = ld4(W, base + 12 + 4 * q);
#pragma unroll
          for (int e = 0; e < 4; e++) a1 = fdot2f(w.h[e], rp[4 * q + e], a1);
        }
        float n0 = fmaxf(fmaf(bx.f[2], (float)X[s][op][0], a0), 0.f);
        float n1 = fmaxf(fmaf(bx.f[3], (float)X[s][op][1], a1), 0.f);
        X[s][op] = pk(n0, n1);
      }
    }

    // ---- k==0: cf + emb1 -> h, in two 24-wide halves (bounds VGPR peak) ----
    if (k == 0) {
      float hp0[24];
#pragma unroll
      for (int hf = 0; hf < 2; hf++) {
        float tv[24];
#pragma unroll
        for (int o2 = 0; o2 < 24; o2++) tv[o2] = W[F_BCF + hf * 24 + o2];
#pragma unroll
        for (int s = 0; s < 2; s++) {
#pragma unroll
          for (int cp = 0; cp < 24; cp++) {
            float x0c = (float)X[s][cp][0], x1c = (float)X[s][cp][1];
            const float* wa = &W[F_CFT + (s * 48 + 2 * cp) * 48 + hf * 24];
            const float* wb = wa + 48;
#pragma unroll
            for (int o2 = 0; o2 < 24; o2++) tv[o2] = fmaf(wa[o2], x0c, fmaf(wb[o2], x1c, tv[o2]));
          }
        }
#pragma unroll
        for (int o2 = 0; o2 < 24; o2++) tv[o2] = fmaxf(tv[o2], 0.f);
#pragma unroll
        for (int o = 0; o < 24; o++) {
          float a = (hf == 0) ? W[F_BE1 + o] : hp0[o];
          const float* w0 = &W[F_WE1 + o * 48 + hf * 24];
#pragma unroll
          for (int c2 = 0; c2 < 24; c2++) a = fmaf(w0[c2], tv[c2], a);
          hp0[o] = a;
        }
      }
#pragma unroll
      for (int o = 0; o < 24; o++) h[o] = gelu_f(hp0[o]);
    }

    // ---- scores ----
    float s1[4], s2[4];
    {
      U4 e4 = ld4(W, F_E4);
      float b1a = e4.f[0], b1b = e4.f[1], b2a = e4.f[2], b2b = e4.f[3];
#pragma unroll
      for (int j = 0; j < 24; j++) {
        U4 d = ld4(W, F_D4 + 4 * j);
        b1a = fmaf(d.f[0], h[j], b1a);
        b1b = fmaf(d.f[1], h[j], b1b);
        b2a = fmaf(d.f[2], h[j], b2a);
        b2b = fmaf(d.f[3], h[j], b2b);
      }
      s1[0] = b1a; s1[2] = b1a; s1[1] = b1b; s1[3] = b1b;
      s2[0] = b2a; s2[2] = b2a; s2[1] = b2b; s2[3] = b2b;
    }
    h2 hp[12];
#pragma unroll
    for (int j = 0; j < 12; j++) hp[j] = pk(h[2 * j], h[2 * j + 1]);

#pragma unroll
    for (int cp = 0; cp < 24; cp++) {
      h2 u0 = X[0][cp], u1 = X[1][cp];
#pragma unroll
      for (int ch = 0; ch < 2; ch++) {
        const int c = 2 * cp + ch;
        const int base = H_SC + c * 52;
        U4 cc = ld4(W, base + 48);
        float z1a = cc.f[0], z1b = cc.f[1], z2a = cc.f[2], z2b = cc.f[3];
#pragma unroll
        for (int q = 0; q < 3; q++) {
          U4 w = ld4(W, base + 4 * q);
#pragma unroll
          for (int e = 0; e < 4; e++) z1a = fdot2f(w.h[e], hp[4 * q + e], z1a);
        }
#pragma unroll
        for (int q = 0; q < 3; q++) {
          U4 w = ld4(W, base + 12 + 4 * q);
#pragma unroll
          for (int e = 0; e < 4; e++) z1b = fdot2f(w.h[e], hp[4 * q + e], z1b);
        }
#pragma unroll
        for (int q = 0; q < 3; q++) {
          U4 w = ld4(W, base + 24 + 4 * q);
#pragma unroll
          for (int e = 0; e < 4; e++) z2a = fdot2f(w.h[e], hp[4 * q + e], z2a);
        }
#pragma unroll
        for (int q = 0; q < 3; q++) {
          U4 w = ld4(W, base + 36 + 4 * q);
#pragma unroll
          for (int e = 0; e < 4; e++) z2b = fdot2f(w.h[e], hp[4 * q + e], z2b);
        }
        float x0 = (float)(ch ? u0[1] : u0[0]);
        float x1 = (float)(ch ? u1[1] : u1[0]);
        s1[0] = fmaf(x0, z1a, s1[0]); s1[1] = fmaf(x0, z1b, s1[1]);
        s1[2] = fmaf(x1, z1a, s1[2]); s1[3] = fmaf(x1, z1b, s1[3]);
        s2[0] = fmaf(x0, z2a, s2[0]); s2[1] = fmaf(x0, z2b, s2[1]);
        s2[2] = fmaf(x1, z2a, s2[2]); s2[3] = fmaf(x1, z2b, s2[3]);
      }
    }
    // softmax over 4
    {
      float m1 = fmaxf(fmaxf(s1[0], s1[1]), fmaxf(s1[2], s1[3]));
      float e0 = __expf(s1[0] - m1), e1 = __expf(s1[1] - m1), e2 = __expf(s1[2] - m1), e3 = __expf(s1[3] - m1);
      float inv = 1.f / (e0 + e1 + e2 + e3);
      s1[0] = e0 * inv; s1[1] = e1 * inv; s1[2] = e2 * inv; s1[3] = e3 * inv;
      float m2 = fmaxf(fmaxf(s2[0], s2[1]), fmaxf(s2[2], s2[3]));
      float f0 = __expf(s2[0] - m2), f1 = __expf(s2[1] - m2), f2 = __expf(s2[2] - m2), f3 = __expf(s2[3] - m2);
      float jnv = 1.f / (f0 + f1 + f2 + f3);
      s2[0] = f0 * jnv; s2[1] = f1 * jnv; s2[2] = f2 * jnv; s2[3] = f3 * jnv;
    }

    // ---- values fused with emb1 ----
    float hv[24];
    {
      float q1l = s1[0] + s1[2], q1h = s1[1] + s1[3];
      float q2l = s2[0] + s2[2], q2h = s2[1] + s2[3];
#pragma unroll
      for (int o = 0; o < 24; o++) {
        U4 qq = ld4(W, F_Q4 + 4 * o);
        hv[o] = fmaf(q1l, qq.f[0], fmaf(q1h, qq.f[1], fmaf(q2l, qq.f[2], fmaf(q2h, qq.f[3], W[F_BE1 + o]))));
      }
    }
#pragma unroll
    for (int cp = 0; cp < 24; cp++) {
      h2 u0 = X[0][cp], u1 = X[1][cp];
#pragma unroll
      for (int ch = 0; ch < 2; ch++) {
        const int c = 2 * cp + ch;
        float x0 = (float)(ch ? u0[1] : u0[0]);
        float x1 = (float)(ch ? u1[1] : u1[0]);
        float cA = fmaf(s1[0], x0, s1[2] * x1);
        float cB = fmaf(s1[1], x0, s1[3] * x1);
        float cC = fmaf(s2[0], x0, s2[2] * x1);
        float cD = fmaf(s2[1], x0, s2[3] * x1);
        h2 pAB = pk(cA, cB), pCD = pk(cC, cD);
        const int base = H_PV + c * 48;
#pragma unroll
        for (int q = 0; q < 6; q++) {
          U4 w = ld4(W, base + 4 * q);
#pragma unroll
          for (int e = 0; e < 4; e++) hv[4 * q + e] = fdot2f(w.h[e], pAB, hv[4 * q + e]);
        }
#pragma unroll
        for (int q = 0; q < 6; q++) {
          U4 w = ld4(W, base + 24 + 4 * q);
#pragma unroll
          for (int e = 0; e < 4; e++) hv[4 * q + e] = fdot2f(w.h[e], pCD, hv[4 * q + e]);
        }
      }
    }
#pragma unroll
    for (int o = 0; o < 24; o++) h[o] = gelu_f(hv[o]);
  }

  // ---- final: out = WE2 h + BE2 ----
  float* po = out + (size_t)b * 48 * HWS + n;
#pragma unroll 1
  for (int op = 0; op < 24; op++) {
    const float* w0 = &W[F_WE2 + op * 52];
    float a0 = w0[48], a1 = w0[49];
#pragma unroll
    for (int j = 0; j < 24; j++) a0 = fmaf(w0[j], h[j], a0);
#pragma unroll
    for (int j = 0; j < 24; j++) a1 = fmaf(w0[24 + j], h[j], a1);
    po[(size_t)(2 * op) * HWS] = a0;
    po[(size_t)(2 * op + 1) * HWS] = a1;
  }
}

extern "C" void kernel_launch(void* const* d_in, const int* in_sizes, int n_in,
                              void* d_out, int out_size, void* d_ws, size_t ws_size,
                              hipStream_t stream) {
  PtrPack P;
  for (int i = 0; i < 48; i++) P.p[i] = (const float*)d_in[i];
  float* W = (float*)d_ws;

  fold_kernel<<<(WS_TOTAL + 255) / 256, 256, 0, stream>>>(P, W);
  fused_main<<<NPIX / T, T, 0, stream>>>(P.p[0], P.p[1], W, (float*)d_out);
}

// Round 19
// 571.910 us; speedup vs baseline: 5.4803x; 5.4803x over previous
//
#include <hip/hip_runtime.h>
#include <hip/hip_fp16.h>
#include <stdint.h>
#include <math.h>

#define HWS 16384
#define NPIX (16 * HWS)
#define T 256

typedef _Float16 h2 __attribute__((ext_vector_type(2)));

// d_ws slot offsets (4B slots). H_* hold packed fp16 pairs; F_* are fp32.
enum {
  H_W1P = 0,     // [24cp][24o]  rb1, pair over input channels (matches X pairs)
  F_B1  = 576,   // 24
  H_W2P = 600,   // [48o][12cj]  rb2, pair over r channels
  F_B2  = 1176,  // 48
  F_XS  = 1224,  // 48
  H_M1A = 1272,  // [48c][12jp]  score folds, pair over h
  H_M1B = 1848,
  H_M2A = 2424,
  H_M2B = 3000,
  F_C1A = 3576, F_C1B = 3624, F_C2A = 3672, F_C2B = 3720,   // 48 each
  F_D1A = 3768, F_D1B = 3792, F_D2A = 3816, F_D2B = 3840,   // 24 each
  F_E4  = 3864,  // 4
  H_P1  = 3868,  // [48c][24o] = (p1l,p1h) pairs
  H_P2  = 5020,  // [48c][24o] = (p2l,p2h) pairs
  F_Q1L = 6172, F_Q1H = 6196, F_Q2L = 6220, F_Q2H = 6244,   // 24 each
  F_BE1 = 6268,  // 24
  F_CFT = 6292,  // f32 [96][48] (k0 only)
  F_BCF = 10900, // 48
  F_WE1 = 10948, // f32 [24][48] (k0 only)
  F_BE2 = 12100, // 48
  F_WE2R= 12148, // f32 [48][24] (final only)
  WS_TOTAL = 13300
};

struct PtrPack { const float* p[48]; };

__device__ __forceinline__ void bnst(const PtrPack& P, int bnb, int o, float& s, float& t) {
  float g = P.p[bnb][o], be = P.p[bnb + 1][o], m = P.p[bnb + 2][o], v = P.p[bnb + 3][o];
  s = g / sqrtf(v + 1e-5f);
  t = be - m * s;
}
__device__ __forceinline__ float KFv(const PtrPack& P, const float* kw, int bnb, int ok, int j) {
  float s, t; bnst(P, bnb, ok, s, t);
  float a = 0.f;
  for (int cc = 0; cc < 48; cc++) a += kw[ok * 48 + cc] * P.p[46][cc * 24 + j];
  return s * a;
}
__device__ __forceinline__ float BFv(const PtrPack& P, const float* kw, const float* kb, int bnb, int ok) {
  float s, t; bnst(P, bnb, ok, s, t);
  float a = kb[ok];
  for (int cc = 0; cc < 48; cc++) a += kw[ok * 48 + cc] * P.p[47][cc];
  return s * a + t;
}
__device__ __forceinline__ float WQf(const PtrPack& P, int o, int c) { float s, t; bnst(P, 16, o, s, t); return s * P.p[14][o * 48 + c]; }
__device__ __forceinline__ float BQf(const PtrPack& P, int o) { float s, t; bnst(P, 16, o, s, t); return s * P.p[15][o] + t; }
__device__ __forceinline__ float WVf(const PtrPack& P, int o, int c) { float s, t; bnst(P, 22, o, s, t); return s * P.p[20][o * 48 + c]; }
__device__ __forceinline__ float BVf(const PtrPack& P, int o) { float s, t; bnst(P, 22, o, s, t); return s * P.p[21][o] + t; }

__device__ float w1v(const PtrPack& P, int c, int o) { float s, t; bnst(P, 4, o, s, t); return s * P.p[2][o * 48 + c]; }
__device__ float w2v(const PtrPack& P, int o, int c) { float s, t; bnst(P, 10, o, s, t); return s * P.p[8][o * 24 + c]; }
__device__ float m_v(const PtrPack& P, int which, int c, int j) {
  float a = 0.f;
  if (which == 0)      for (int ok = 0; ok < 24; ok++) a += KFv(P, P.p[26], 28, ok, j) * WQf(P, ok, c);
  else if (which == 1) for (int ok = 0; ok < 24; ok++) a += KFv(P, P.p[26], 28, ok, j) * WQf(P, 24 + ok, c);
  else if (which == 2) for (int ok = 0; ok < 24; ok++) a += KFv(P, P.p[32], 34, ok, j) * WQf(P, ok, c);
  else                 for (int ok = 0; ok < 24; ok++) a += KFv(P, P.p[32], 34, ok, j) * WQf(P, 24 + ok, c);
  return a;
}
__device__ float p_v(const PtrPack& P, int which, int c, int o) {
  float a = 0.f;
  if (which == 0)      for (int jj = 0; jj < 24; jj++) a += P.p[44][o * 48 + jj] * WVf(P, jj, c);
  else if (which == 1) for (int jj = 0; jj < 24; jj++) a += P.p[44][o * 48 + jj] * WVf(P, 24 + jj, c);
  else if (which == 2) for (int jj = 0; jj < 24; jj++) a += P.p[44][o * 48 + 24 + jj] * WVf(P, jj, c);
  else                 for (int jj = 0; jj < 24; jj++) a += P.p[44][o * 48 + 24 + jj] * WVf(P, 24 + jj, c);
  return a;
}

__device__ __forceinline__ float packh2(float a, float b) {
  __half2 h = __floats2half2_rn(a, b);
  union { __half2 h; float f; } x; x.h = h; return x.f;
}

__global__ void fold_kernel(PtrPack P, float* __restrict__ W) {
  int i = blockIdx.x * blockDim.x + threadIdx.x;
  if (i >= WS_TOTAL) return;
  float s, t, a;
  if (i < F_B1)        { int cp = i / 24, o = i % 24; W[i] = packh2(w1v(P, 2 * cp, o), w1v(P, 2 * cp + 1, o)); }
  else if (i < H_W2P)  { int o = i - F_B1; bnst(P, 4, o, s, t); W[i] = s * P.p[3][o] + t; }
  else if (i < F_B2)   { int j = i - H_W2P; int o = j / 12, cj = j % 12; W[i] = packh2(w2v(P, o, 2 * cj), w2v(P, o, 2 * cj + 1)); }
  else if (i < F_XS)   { int o = i - F_B2; bnst(P, 10, o, s, t); W[i] = s * P.p[9][o] + t; }
  else if (i < H_M1A)  { int o = i - F_XS; bnst(P, 10, o, s, t); W[i] = s; }
  else if (i < H_M1B)  { int j = i - H_M1A; int c = j / 12, jp = j % 12; W[i] = packh2(m_v(P, 0, c, 2 * jp), m_v(P, 0, c, 2 * jp + 1)); }
  else if (i < H_M2A)  { int j = i - H_M1B; int c = j / 12, jp = j % 12; W[i] = packh2(m_v(P, 1, c, 2 * jp), m_v(P, 1, c, 2 * jp + 1)); }
  else if (i < H_M2B)  { int j = i - H_M2A; int c = j / 12, jp = j % 12; W[i] = packh2(m_v(P, 2, c, 2 * jp), m_v(P, 2, c, 2 * jp + 1)); }
  else if (i < F_C1A)  { int j = i - H_M2B; int c = j / 12, jp = j % 12; W[i] = packh2(m_v(P, 3, c, 2 * jp), m_v(P, 3, c, 2 * jp + 1)); }
  else if (i < F_C1B)  { int c = i - F_C1A; a = 0.f; for (int ok = 0; ok < 24; ok++) a += BFv(P, P.p[26], P.p[27], 28, ok) * WQf(P, ok, c); W[i] = a; }
  else if (i < F_C2A)  { int c = i - F_C1B; a = 0.f; for (int ok = 0; ok < 24; ok++) a += BFv(P, P.p[26], P.p[27], 28, ok) * WQf(P, 24 + ok, c); W[i] = a; }
  else if (i < F_C2B)  { int c = i - F_C2A; a = 0.f; for (int ok = 0; ok < 24; ok++) a += BFv(P, P.p[32], P.p[33], 34, ok) * WQf(P, ok, c); W[i] = a; }
  else if (i < F_D1A)  { int c = i - F_C2B; a = 0.f; for (int ok = 0; ok < 24; ok++) a += BFv(P, P.p[32], P.p[33], 34, ok) * WQf(P, 24 + ok, c); W[i] = a; }
  else if (i < F_D1B)  { int j = i - F_D1A; a = 0.f; for (int ok = 0; ok < 24; ok++) a += KFv(P, P.p[26], 28, ok, j) * BQf(P, ok); W[i] = a; }
  else if (i < F_D2A)  { int j = i - F_D1B; a = 0.f; for (int ok = 0; ok < 24; ok++) a += KFv(P, P.p[26], 28, ok, j) * BQf(P, 24 + ok); W[i] = a; }
  else if (i < F_D2B)  { int j = i - F_D2A; a = 0.f; for (int ok = 0; ok < 24; ok++) a += KFv(P, P.p[32], 34, ok, j) * BQf(P, ok); W[i] = a; }
  else if (i < F_E4)   { int j = i - F_D2B; a = 0.f; for (int ok = 0; ok < 24; ok++) a += KFv(P, P.p[32], 34, ok, j) * BQf(P, 24 + ok); W[i] = a; }
  else if (i < H_P1)   { int e = i - F_E4; a = 0.f;
    if (e == 0)      for (int ok = 0; ok < 24; ok++) a += BFv(P, P.p[26], P.p[27], 28, ok) * BQf(P, ok);
    else if (e == 1) for (int ok = 0; ok < 24; ok++) a += BFv(P, P.p[26], P.p[27], 28, ok) * BQf(P, 24 + ok);
    else if (e == 2) for (int ok = 0; ok < 24; ok++) a += BFv(P, P.p[32], P.p[33], 34, ok) * BQf(P, ok);
    else             for (int ok = 0; ok < 24; ok++) a += BFv(P, P.p[32], P.p[33], 34, ok) * BQf(P, 24 + ok);
    W[i] = a; }
  else if (i < H_P2)   { int j = i - H_P1; int c = j / 24, o = j % 24; W[i] = packh2(p_v(P, 0, c, o), p_v(P, 1, c, o)); }
  else if (i < F_Q1L)  { int j = i - H_P2; int c = j / 24, o = j % 24; W[i] = packh2(p_v(P, 2, c, o), p_v(P, 3, c, o)); }
  else if (i < F_Q1H)  { int o = i - F_Q1L; a = 0.f; for (int jj = 0; jj < 24; jj++) a += P.p[44][o * 48 + jj] * BVf(P, jj); W[i] = a; }
  else if (i < F_Q2L)  { int o = i - F_Q1H; a = 0.f; for (int jj = 0; jj < 24; jj++) a += P.p[44][o * 48 + jj] * BVf(P, 24 + jj); W[i] = a; }
  else if (i < F_Q2H)  { int o = i - F_Q2L; a = 0.f; for (int jj = 0; jj < 24; jj++) a += P.p[44][o * 48 + 24 + jj] * BVf(P, jj); W[i] = a; }
  else if (i < F_BE1)  { int o = i - F_Q2H; a = 0.f; for (int jj = 0; jj < 24; jj++) a += P.p[44][o * 48 + 24 + jj] * BVf(P, 24 + jj); W[i] = a; }
  else if (i < F_CFT)  { int o = i - F_BE1; W[i] = P.p[45][o]; }
  else if (i < F_BCF)  { int j = i - F_CFT; int cin = j / 48, o = j % 48; bnst(P, 40, o, s, t); W[i] = s * P.p[38][o * 96 + cin]; }
  else if (i < F_WE1)  { int o = i - F_BCF; bnst(P, 40, o, s, t); W[i] = s * P.p[39][o] + t; }
  else if (i < F_BE2)  { int j = i - F_WE1; W[i] = P.p[44][j]; }
  else if (i < F_WE2R) { int o = i - F_BE2; W[i] = P.p[47][o]; }
  else                 { int j = i - F_WE2R; W[i] = P.p[46][j]; }
}

// ---------------- fused per-pixel forward (dot2 hot loops) ----------------

__device__ __forceinline__ float gelu_f(float x) {
  return 0.5f * x * (1.f + erff(x * 0.70710678118654752440f));
}
__device__ __forceinline__ float fdot2f(h2 a, h2 b, float c) {
#if __has_builtin(__builtin_amdgcn_fdot2)
  return __builtin_amdgcn_fdot2(a, b, c, false);
#else
  return fmaf((float)a[0], (float)b[0], fmaf((float)a[1], (float)b[1], c));
#endif
}
__device__ __forceinline__ h2 ldh(const float* __restrict__ W, int off) {
  union { float f; h2 h; } u; u.f = W[off]; return u.h;
}
__device__ __forceinline__ h2 ash2(__half2 v) {
  union { __half2 a; h2 h; } u; u.a = v; return u.h;
}
// Round-to-nearest-even packing (NOT pkrtz — RTZ's biased truncation pushed
// absmax from 0.094 to 0.174 in round 13).
__device__ __forceinline__ h2 pk(float a, float b) {
  return ash2(__floats2half2_rn(a, b));
}

__global__ __launch_bounds__(T)
void fused_main(const float* __restrict__ x0g,
                const float* __restrict__ x1g,
                const float* __restrict__ W,
                float* __restrict__ out) {
  __shared__ __half2 Xh[2][24][T];
  const int tid = threadIdx.x;
  const int p = blockIdx.x * T + tid;
  const int b = p >> 14;
  const int n = p & (HWS - 1);

  {
    const float* px0 = x0g + (size_t)b * 48 * HWS + n;
    const float* px1 = x1g + (size_t)b * 48 * HWS + n;
#pragma unroll 1
    for (int cp = 0; cp < 24; cp++) {
      Xh[0][cp][tid] = __floats2half2_rn(px0[(size_t)(2 * cp) * HWS], px0[(size_t)(2 * cp + 1) * HWS]);
      Xh[1][cp][tid] = __floats2half2_rn(px1[(size_t)(2 * cp) * HWS], px1[(size_t)(2 * cp + 1) * HWS]);
    }
  }

  float h[24];

#pragma unroll 1
  for (int k = 0; k < 4; k++) {
    // ---- residual blocks ----
#pragma unroll 1
    for (int s = 0; s < 2; s++) {
      float r[24];
#pragma unroll
      for (int o = 0; o < 24; o++) r[o] = W[F_B1 + o];
#pragma unroll 2
      for (int cp = 0; cp < 24; cp++) {
        h2 xp = ash2(Xh[s][cp][tid]);
#pragma unroll
        for (int o = 0; o < 24; o++) r[o] = fdot2f(ldh(W, H_W1P + cp * 24 + o), xp, r[o]);
      }
#pragma unroll
      for (int o = 0; o < 24; o++) r[o] = fmaxf(r[o], 0.f);
      h2 rp[12];
#pragma unroll
      for (int j = 0; j < 12; j++) rp[j] = pk(r[2 * j], r[2 * j + 1]);

#pragma unroll 2
      for (int op = 0; op < 24; op++) {
        float a0 = W[F_B2 + 2 * op], a1 = W[F_B2 + 2 * op + 1];
#pragma unroll
        for (int cj = 0; cj < 12; cj++) a0 = fdot2f(ldh(W, H_W2P + (2 * op) * 12 + cj), rp[cj], a0);
#pragma unroll
        for (int cj = 0; cj < 12; cj++) a1 = fdot2f(ldh(W, H_W2P + (2 * op + 1) * 12 + cj), rp[cj], a1);
        __half2 u = Xh[s][op][tid];
        float n0 = fmaxf(fmaf(W[F_XS + 2 * op], __low2float(u), a0), 0.f);
        float n1 = fmaxf(fmaf(W[F_XS + 2 * op + 1], __high2float(u), a1), 0.f);
        Xh[s][op][tid] = __floats2half2_rn(n0, n1);
      }
    }

    // ---- k==0: cf + emb1 -> h (fp32 tables, runs once) ----
    if (k == 0) {
      float tv[48];
#pragma unroll
      for (int o = 0; o < 48; o++) tv[o] = W[F_BCF + o];
#pragma unroll 1
      for (int s = 0; s < 2; s++) {
#pragma unroll 1
        for (int cp = 0; cp < 24; cp++) {
          __half2 u = Xh[s][cp][tid];
          float x0c = __low2float(u), x1c = __high2float(u);
          const float* w0 = &W[F_CFT + (s * 48 + 2 * cp) * 48];
#pragma unroll
          for (int o = 0; o < 48; o++) tv[o] = fmaf(w0[o], x0c, tv[o]);
#pragma unroll
          for (int o = 0; o < 48; o++) tv[o] = fmaf(w0[48 + o], x1c, tv[o]);
        }
      }
#pragma unroll
      for (int o = 0; o < 48; o++) tv[o] = fmaxf(tv[o], 0.f);
#pragma unroll
      for (int o = 0; o < 24; o++) {
        float a = W[F_BE1 + o];
#pragma unroll
        for (int c = 0; c < 48; c++) a = fmaf(W[F_WE1 + o * 48 + c], tv[c], a);
        h[o] = gelu_f(a);
      }
    }

    // ---- scores ----
    float s1[4], s2[4];
    {
      float b1a = W[F_E4 + 0], b1b = W[F_E4 + 1], b2a = W[F_E4 + 2], b2b = W[F_E4 + 3];
#pragma unroll
      for (int j = 0; j < 24; j++) {
        b1a = fmaf(W[F_D1A + j], h[j], b1a);
        b1b = fmaf(W[F_D1B + j], h[j], b1b);
        b2a = fmaf(W[F_D2A + j], h[j], b2a);
        b2b = fmaf(W[F_D2B + j], h[j], b2b);
      }
      s1[0] = b1a; s1[2] = b1a; s1[1] = b1b; s1[3] = b1b;
      s2[0] = b2a; s2[2] = b2a; s2[1] = b2b; s2[3] = b2b;
    }
    h2 hp[12];
#pragma unroll
    for (int j = 0; j < 12; j++) hp[j] = pk(h[2 * j], h[2 * j + 1]);

#pragma unroll 2
    for (int cp = 0; cp < 24; cp++) {
      __half2 u0 = Xh[0][cp][tid], u1 = Xh[1][cp][tid];
#pragma unroll
      for (int ch = 0; ch < 2; ch++) {
        int c = 2 * cp + ch;
        float z1a = W[F_C1A + c], z1b = W[F_C1B + c];
        float z2a = W[F_C2A + c], z2b = W[F_C2B + c];
#pragma unroll
        for (int jp = 0; jp < 12; jp++) {
          z1a = fdot2f(ldh(W, H_M1A + c * 12 + jp), hp[jp], z1a);
          z1b = fdot2f(ldh(W, H_M1B + c * 12 + jp), hp[jp], z1b);
          z2a = fdot2f(ldh(W, H_M2A + c * 12 + jp), hp[jp], z2a);
          z2b = fdot2f(ldh(W, H_M2B + c * 12 + jp), hp[jp], z2b);
        }
        float x0 = ch ? __high2float(u0) : __low2float(u0);
        float x1 = ch ? __high2float(u1) : __low2float(u1);
        s1[0] = fmaf(x0, z1a, s1[0]); s1[1] = fmaf(x0, z1b, s1[1]);
        s1[2] = fmaf(x1, z1a, s1[2]); s1[3] = fmaf(x1, z1b, s1[3]);
        s2[0] = fmaf(x0, z2a, s2[0]); s2[1] = fmaf(x0, z2b, s2[1]);
        s2[2] = fmaf(x1, z2a, s2[2]); s2[3] = fmaf(x1, z2b, s2[3]);
      }
    }
    // softmax over 4
    {
      float m1 = fmaxf(fmaxf(s1[0], s1[1]), fmaxf(s1[2], s1[3]));
      float e0 = __expf(s1[0] - m1), e1 = __expf(s1[1] - m1), e2 = __expf(s1[2] - m1), e3 = __expf(s1[3] - m1);
      float inv = 1.f / (e0 + e1 + e2 + e3);
      s1[0] = e0 * inv; s1[1] = e1 * inv; s1[2] = e2 * inv; s1[3] = e3 * inv;
      float m2 = fmaxf(fmaxf(s2[0], s2[1]), fmaxf(s2[2], s2[3]));
      float f0 = __expf(s2[0] - m2), f1 = __expf(s2[1] - m2), f2 = __expf(s2[2] - m2), f3 = __expf(s2[3] - m2);
      float jnv = 1.f / (f0 + f1 + f2 + f3);
      s2[0] = f0 * jnv; s2[1] = f1 * jnv; s2[2] = f2 * jnv; s2[3] = f3 * jnv;
    }

    // ---- values fused with emb1 ----
    float hv[24];
    {
      float q1l = s1[0] + s1[2], q1h = s1[1] + s1[3];
      float q2l = s2[0] + s2[2], q2h = s2[1] + s2[3];
#pragma unroll
      for (int o = 0; o < 24; o++) {
        float a = W[F_BE1 + o];
        a = fmaf(q1l, W[F_Q1L + o], a);
        a = fmaf(q1h, W[F_Q1H + o], a);
        a = fmaf(q2l, W[F_Q2L + o], a);
        a = fmaf(q2h, W[F_Q2H + o], a);
        hv[o] = a;
      }
    }
#pragma unroll 2
    for (int cp = 0; cp < 24; cp++) {
      __half2 u0 = Xh[0][cp][tid], u1 = Xh[1][cp][tid];
#pragma unroll
      for (int ch = 0; ch < 2; ch++) {
        int c = 2 * cp + ch;
        float x0 = ch ? __high2float(u0) : __low2float(u0);
        float x1 = ch ? __high2float(u1) : __low2float(u1);
        float cA = fmaf(s1[0], x0, s1[2] * x1);
        float cB = fmaf(s1[1], x0, s1[3] * x1);
        float cC = fmaf(s2[0], x0, s2[2] * x1);
        float cD = fmaf(s2[1], x0, s2[3] * x1);
        h2 pAB = pk(cA, cB), pCD = pk(cC, cD);
#pragma unroll
        for (int o = 0; o < 24; o++) {
          float a = hv[o];
          a = fdot2f(ldh(W, H_P1 + c * 24 + o), pAB, a);
          a = fdot2f(ldh(W, H_P2 + c * 24 + o), pCD, a);
          hv[o] = a;
        }
      }
    }
#pragma unroll
    for (int o = 0; o < 24; o++) h[o] = gelu_f(hv[o]);
  }

  // ---- final: out = WE2 h + BE2 (fp32) ----
  float* po = out + (size_t)b * 48 * HWS + n;
#pragma unroll 1
  for (int op = 0; op < 24; op++) {
    const float* w0 = &W[F_WE2R + (2 * op) * 24];
    float a0 = W[F_BE2 + 2 * op], a1 = W[F_BE2 + 2 * op + 1];
#pragma unroll
    for (int j = 0; j < 24; j++) a0 = fmaf(w0[j], h[j], a0);
#pragma unroll
    for (int j = 0; j < 24; j++) a1 = fmaf(w0[24 + j], h[j], a1);
    po[(size_t)(2 * op) * HWS] = a0;
    po[(size_t)(2 * op + 1) * HWS] = a1;
  }
}

extern "C" void kernel_launch(void* const* d_in, const int* in_sizes, int n_in,
                              void* d_out, int out_size, void* d_ws, size_t ws_size,
                              hipStream_t stream) {
  PtrPack P;
  for (int i = 0; i < 48; i++) P.p[i] = (const float*)d_in[i];
  float* W = (float*)d_ws;

  fold_kernel<<<(WS_TOTAL + 255) / 256, 256, 0, stream>>>(P, W);
  fused_main<<<NPIX / T, T, 0, stream>>>(P.p[0], P.p[1], W, (float*)d_out);
}